// Round 2
// baseline (1027.917 us; speedup 1.0000x reference)
//
#include <hip/hip_runtime.h>

typedef unsigned short u16;
typedef unsigned int   u32;
typedef __attribute__((ext_vector_type(4))) float f32x4;
typedef __attribute__((ext_vector_type(8))) short s16x8;
typedef __attribute__((ext_vector_type(4))) unsigned short u16x4;

#define FLATD 251968   // 64*31*127
#define LIN1  251992   // FLATD + 24
#define K_    251968

// round-to-nearest-even f32 -> bf16
__device__ __forceinline__ u16 f2bf(float f) {
  u32 u = __float_as_uint(f);
  u32 r = (u + 0x7fffu + ((u >> 16) & 1u)) >> 16;
  return (u16)r;
}

// ---------------------------------------------------------------------------
// K1: per-batch attention + 2x2 conv + relu -> flat (bf16)
// ---------------------------------------------------------------------------
__global__ __launch_bounds__(256) void k_attn_conv(
    const float* __restrict__ Xn, const float* __restrict__ Wa,
    const float* __restrict__ Ua, const float* __restrict__ Va,
    const float* __restrict__ cw, const float* __restrict__ cb,
    u16* __restrict__ flat)
{
  __shared__ float Xs[32][65];   // pad 65: bank-conflict-free column reads
  __shared__ float Xw[32][65];
  __shared__ float Xu[32][65];
  __shared__ float ev[32][33];
  __shared__ float Vs[64];
  __shared__ float ins[32][132]; // conv input [X | c], padded

  const int b = blockIdx.x;
  const int t = threadIdx.x;
  const float* xb = Xn + (size_t)b * 2048;

  for (int v = t; v < 512; v += 256) {
    float4 x = ((const float4*)xb)[v];
    int row = v >> 4, c4 = (v & 15) << 2;
    Xs[row][c4] = x.x; Xs[row][c4 + 1] = x.y; Xs[row][c4 + 2] = x.z; Xs[row][c4 + 3] = x.w;
  }
  if (t < 64) Vs[t] = Va[t];
  __syncthreads();

  // Xw = X@W, Xu = X@U.  h = lane (fixed per thread) -> W/U column regs reused 8x.
  {
    const int h = t & 63, iw = t >> 6;
    float aw[8] = {0,0,0,0,0,0,0,0}, au[8] = {0,0,0,0,0,0,0,0};
    for (int f = 0; f < 64; ++f) {
      float wv_ = Wa[f * 64 + h], uv_ = Ua[f * 64 + h];
#pragma unroll
      for (int s = 0; s < 8; ++s) {
        float x = Xs[iw + 4 * s][f];
        aw[s] = fmaf(x, wv_, aw[s]);
        au[s] = fmaf(x, uv_, au[s]);
      }
    }
#pragma unroll
    for (int s = 0; s < 8; ++s) { Xw[iw + 4 * s][h] = aw[s]; Xu[iw + 4 * s][h] = au[s]; }
  }
  __syncthreads();

  // e[i][j] = sum_h tanh(Xw[i][h]+Xu[j][h]) * V[h]
  for (int p = t; p < 1024; p += 256) {
    int i = p >> 5, j = p & 31;
    float acc = 0.f;
    for (int h = 0; h < 64; ++h) {
      float s  = Xw[i][h] + Xu[j][h];
      float ex = __expf(2.f * s);
      float th = 1.f - 2.f * __builtin_amdgcn_rcpf(ex + 1.f);
      acc = fmaf(th, Vs[h], acc);
    }
    ev[i][j] = acc;
  }
  __syncthreads();

  // softmax over j: 32 rows x 8 threads
  {
    int i = t >> 3, g = t & 7;
    float e0 = ev[i][g], e1 = ev[i][g + 8], e2 = ev[i][g + 16], e3 = ev[i][g + 24];
    float m = fmaxf(fmaxf(e0, e1), fmaxf(e2, e3));
    m = fmaxf(m, __shfl_xor(m, 1));
    m = fmaxf(m, __shfl_xor(m, 2));
    m = fmaxf(m, __shfl_xor(m, 4));
    float p0 = __expf(e0 - m), p1 = __expf(e1 - m), p2 = __expf(e2 - m), p3 = __expf(e3 - m);
    float s = p0 + p1 + p2 + p3;
    s += __shfl_xor(s, 1); s += __shfl_xor(s, 2); s += __shfl_xor(s, 4);
    float inv = __builtin_amdgcn_rcpf(s);
    ev[i][g] = p0 * inv; ev[i][g + 8] = p1 * inv; ev[i][g + 16] = p2 * inv; ev[i][g + 24] = p3 * inv;
  }
  __syncthreads();

  // c = alpha@X - diag(alpha)*X ; ins = [X | c]
  for (int p = t; p < 2048; p += 256) {
    int i = p >> 6, f = p & 63;
    float acc = 0.f;
#pragma unroll 8
    for (int j = 0; j < 32; ++j) acc = fmaf(ev[i][j], Xs[j][f], acc);
    acc -= ev[i][i] * Xs[i][f];
    ins[i][f]      = Xs[i][f];
    ins[i][64 + f] = acc;
  }
  __syncthreads();

  // conv 2x2 VALID + relu -> flat bf16 (k = f*3937 + r*127 + c)
  // position outer, 8-filter tile inner: 4 LDS tap reads amortized over 8 filters
  const int lane = t & 63, wv = t >> 6;
  u16* fb = flat + (size_t)b * FLATD;
  for (int fblk = 0; fblk < 8; ++fblk) {
    float w00[8], w01[8], w10[8], w11[8], bb[8];
#pragma unroll
    for (int j = 0; j < 8; ++j) {
      int f = fblk * 8 + j;
      w00[j] = cw[f * 4 + 0]; w01[j] = cw[f * 4 + 1];
      w10[j] = cw[f * 4 + 2]; w11[j] = cw[f * 4 + 3];
      bb[j]  = cb[f];
    }
    for (int s = wv; s < 62; s += 4) {
      int r = s >> 1;
      int c = ((s & 1) << 6) + lane;
      if (c < 127) {
        float x0 = ins[r][c],     x1 = ins[r][c + 1];
        float y0 = ins[r + 1][c], y1 = ins[r + 1][c + 1];
        u16* po = fb + (size_t)(fblk * 8) * 3937 + r * 127 + c;
#pragma unroll
        for (int j = 0; j < 8; ++j) {
          float y = fmaf(x0, w00[j], fmaf(x1, w01[j],
                    fmaf(y0, w10[j], fmaf(y1, w11[j], bb[j]))));
          po[(size_t)j * 3937] = f2bf(fmaxf(y, 0.f));
        }
      }
    }
  }
}

// ---------------------------------------------------------------------------
// K2: w1 (f32, rows of LIN1) -> w1b (bf16, rows of K_, cate tail dropped)
// ---------------------------------------------------------------------------
__global__ __launch_bounds__(256) void k_cast_w1(const float* __restrict__ w1,
                                                 u16* __restrict__ w1b)
{
  const int o = blockIdx.x;     // 256 rows
  const int part = blockIdx.y;  // 8 parts of 7874 float4s
  const int t = threadIdx.x;
  const float4* src = (const float4*)(w1 + (size_t)o * LIN1) + part * 7874;
  u16x4* dst = (u16x4*)(w1b + (size_t)o * K_) + part * 7874;
  for (int i = t; i < 7874; i += 256) {
    float4 v = src[i];
    u16x4 o4;
    o4.x = f2bf(v.x); o4.y = f2bf(v.y); o4.z = f2bf(v.z); o4.w = f2bf(v.w);
    dst[i] = o4;
  }
}

// ---------------------------------------------------------------------------
// K3: x1 = b1 + cate_embedding . w1[:, FLATD:]  (f32, exact)
// ---------------------------------------------------------------------------
__global__ __launch_bounds__(256) void k_cate(
    const int* __restrict__ Xc, const float* __restrict__ e0,
    const float* __restrict__ e1, const float* __restrict__ e2,
    const float* __restrict__ w1, const float* __restrict__ b1,
    float* __restrict__ x1)
{
  __shared__ float es[24];
  const int b = blockIdx.x, t = threadIdx.x;
  if (t < 24) {
    int g = t >> 3, d = t & 7;
    int idx = Xc[b * 3 + g];
    const float* tab = (g == 0) ? e0 : (g == 1) ? e1 : e2;
    es[t] = tab[idx * 8 + d];
  }
  __syncthreads();
  float acc = b1[t];
  const float* wt = w1 + (size_t)t * LIN1 + FLATD;
#pragma unroll
  for (int j = 0; j < 24; ++j) acc = fmaf(es[j], wt[j], acc);
  x1[b * 256 + t] = acc;
}

// ---------------------------------------------------------------------------
// K4: bf16 MFMA GEMM  x1[1024,256] += flat[1024,K] . w1b[256,K]^T
// m97 structure: 128x128 tile, BK=32, 4 waves (2x2, 64x64 each),
// K-split 62 chunks x 127 steps (62*127*32 = 251968 exact).
// grid (16 tiles = nt*8+mt, 62 kc) = 992 blocks (~3.9/CU).
// ---------------------------------------------------------------------------
#define AS1 __attribute__((address_space(1)))
#define AS3 __attribute__((address_space(3)))
__device__ __forceinline__ void g2l16(const void* g, void* l) {
  __builtin_amdgcn_global_load_lds((const AS1 u32*)g, (AS3 u32*)l, 16, 0, 0);
}

__global__ __launch_bounds__(256, 3) void k_gemm(
    const u16* __restrict__ A, const u16* __restrict__ Bw, float* __restrict__ C)
{
  __shared__ u16 As[128 * 32];  // 8 KB, row-major [128][32]
  __shared__ u16 Bs[128 * 32];  // 8 KB
  const int tile = blockIdx.x;  // 16: nt*8 + mt (same-XCD pairs share mt -> A in L2)
  const int kc   = blockIdx.y;  // 62
  const int mt = tile & 7, nt = tile >> 3;
  const int tid = threadIdx.x;
  const int lane = tid & 63, w = tid >> 6;
  const int wm = w >> 1, wn = w & 1;   // 2x2 wave grid, wave tile 64x64

  const size_t kbase = (size_t)kc * 4064;  // 127*32
  const u16* gA = A  + ((size_t)(mt * 128 + w * 32 + (lane >> 2))) * K_ + kbase + (size_t)(lane & 3) * 8;
  const u16* gB = Bw + ((size_t)(nt * 128 + w * 32 + (lane >> 2))) * K_ + kbase + (size_t)(lane & 3) * 8;
  char* lA = (char*)As + w * 2048;  // wave stages its 32 rows (2 instrs of 16 rows)
  char* lB = (char*)Bs + w * 2048;

  f32x4 acc[4][4] = {};

  const int aoff = (wm * 64 + (lane & 15)) * 64 + (lane >> 4) * 16;
  const int boff = (wn * 64 + (lane & 15)) * 64 + (lane >> 4) * 16;

  for (int ks = 0; ks < 127; ++ks) {
    const size_t ko = (size_t)ks * 32;
    g2l16(gA + ko,                    lA);
    g2l16(gA + ko + (size_t)16 * K_,  lA + 1024);
    g2l16(gB + ko,                    lB);
    g2l16(gB + ko + (size_t)16 * K_,  lB + 1024);
    __syncthreads();
    s16x8 af[4], bf[4];
#pragma unroll
    for (int mi = 0; mi < 4; ++mi)
      af[mi] = *(const s16x8*)((const char*)As + aoff + mi * 1024);
#pragma unroll
    for (int ni = 0; ni < 4; ++ni)
      bf[ni] = *(const s16x8*)((const char*)Bs + boff + ni * 1024);
#pragma unroll
    for (int mi = 0; mi < 4; ++mi)
#pragma unroll
      for (int ni = 0; ni < 4; ++ni)
        acc[mi][ni] = __builtin_amdgcn_mfma_f32_16x16x32_bf16(af[mi], bf[ni], acc[mi][ni], 0, 0, 0);
    __syncthreads();
  }

  // D layout (m89-verified): n = lane&15, m = (lane>>4)*4 + reg
  const int m0 = mt * 128 + wm * 64 + ((lane >> 4) << 2);
  const int n0 = nt * 128 + wn * 64 + (lane & 15);
#pragma unroll
  for (int mi = 0; mi < 4; ++mi)
#pragma unroll
    for (int ni = 0; ni < 4; ++ni)
#pragma unroll
      for (int r = 0; r < 4; ++r)
        atomicAdd(C + (size_t)(m0 + mi * 16 + r) * 256 + (n0 + ni * 16), acc[mi][ni][r]);
}

// ---------------------------------------------------------------------------
// K5: out = relu(relu(x1) @ w2^T + b2) @ w3^T + b3
// ---------------------------------------------------------------------------
__global__ __launch_bounds__(64) void k_tail(
    const float* __restrict__ x1, const float* __restrict__ w2, const float* __restrict__ b2,
    const float* __restrict__ w3, const float* __restrict__ b3, float* __restrict__ out)
{
  __shared__ float x2s[32];
  const int b = blockIdx.x, l = threadIdx.x;
  const int j = l & 31, og = l >> 5;
  const float* xb = x1 + b * 256 + og * 128;
  const float* wr = w2 + j * 256 + og * 128;
  float acc = 0.f;
#pragma unroll 4
  for (int i = 0; i < 128; ++i)
    acc = fmaf(fmaxf(xb[i], 0.f), wr[i], acc);
  acc += __shfl_xor(acc, 32);
  if (og == 0) x2s[j] = fmaxf(acc + b2[j], 0.f);
  __syncthreads();
  if (l < 2) {
    float r = b3[l];
#pragma unroll
    for (int q = 0; q < 32; ++q) r = fmaf(x2s[q], w3[l * 32 + q], r);
    out[(size_t)b * 2 + l] = r;
  }
}

// ---------------------------------------------------------------------------
extern "C" void kernel_launch(void* const* d_in, const int* in_sizes, int n_in,
                              void* d_out, int out_size, void* d_ws, size_t ws_size,
                              hipStream_t stream)
{
  const float* Xn = (const float*)d_in[0];
  const int*   Xc = (const int*)d_in[1];
  const float* Wa = (const float*)d_in[2];
  const float* Ua = (const float*)d_in[3];
  const float* Va = (const float*)d_in[4];
  const float* cw = (const float*)d_in[5];
  const float* cb = (const float*)d_in[6];
  const float* e0 = (const float*)d_in[7];
  const float* e1 = (const float*)d_in[8];
  const float* e2 = (const float*)d_in[9];
  const float* w1 = (const float*)d_in[10];
  const float* b1 = (const float*)d_in[11];
  const float* w2 = (const float*)d_in[12];
  const float* b2 = (const float*)d_in[13];
  const float* w3 = (const float*)d_in[14];
  const float* b3 = (const float*)d_in[15];
  float* out = (float*)d_out;

  char* ws = (char*)d_ws;
  u16*   flat = (u16*)ws;                      // 1024*251968*2 = 516,030,464 B
  u16*   w1b  = (u16*)(ws + 516030464ull);     // 256*251968*2  = 129,007,616 B
  float* x1   = (float*)(ws + 645038080ull);   // 1024*256*4    =   1,048,576 B
  if (ws_size < 646086656ull) return;          // insufficient scratch: bail visibly

  k_attn_conv<<<dim3(1024), dim3(256), 0, stream>>>(Xn, Wa, Ua, Va, cw, cb, flat);
  k_cast_w1 <<<dim3(256, 8), dim3(256), 0, stream>>>(w1, w1b);
  k_cate    <<<dim3(1024), dim3(256), 0, stream>>>(Xc, e0, e1, e2, w1, b1, x1);
  k_gemm    <<<dim3(16, 62), dim3(256), 0, stream>>>(flat, w1b, x1);
  k_tail    <<<dim3(1024), dim3(64), 0, stream>>>(x1, w2, b2, w3, b3, out);
}

// Round 6
// 886.978 us; speedup vs baseline: 1.1589x; 1.1589x over previous
//
#include <hip/hip_runtime.h>

typedef unsigned short u16;
typedef unsigned int   u32;
typedef __attribute__((ext_vector_type(4))) float f32x4;
typedef __attribute__((ext_vector_type(8))) short s16x8;
typedef __attribute__((ext_vector_type(4))) unsigned short u16x4;

#define FLATD 251968   // 64*31*127
#define LIN1  251992   // FLATD + 24
#define K_    251968

// round-to-nearest-even f32 -> bf16
__device__ __forceinline__ u16 f2bf(float f) {
  u32 u = __float_as_uint(f);
  u32 r = (u + 0x7fffu + ((u >> 16) & 1u)) >> 16;
  return (u16)r;
}

// ---------------------------------------------------------------------------
// K1: per-batch attention + 2x2 conv + relu -> flat (bf16)
// ---------------------------------------------------------------------------
__global__ __launch_bounds__(256) void k_attn_conv(
    const float* __restrict__ Xn, const float* __restrict__ Wa,
    const float* __restrict__ Ua, const float* __restrict__ Va,
    const float* __restrict__ cw, const float* __restrict__ cb,
    u16* __restrict__ flat)
{
  __shared__ float Xs[32][65];   // pad 65: bank-conflict-free column reads
  __shared__ float Xw[32][65];
  __shared__ float Xu[32][65];
  __shared__ float ev[32][33];
  __shared__ float Vs[64];
  __shared__ float ins[32][132]; // conv input [X | c], padded

  const int b = blockIdx.x;
  const int t = threadIdx.x;
  const float* xb = Xn + (size_t)b * 2048;

  for (int v = t; v < 512; v += 256) {
    float4 x = ((const float4*)xb)[v];
    int row = v >> 4, c4 = (v & 15) << 2;
    Xs[row][c4] = x.x; Xs[row][c4 + 1] = x.y; Xs[row][c4 + 2] = x.z; Xs[row][c4 + 3] = x.w;
  }
  if (t < 64) Vs[t] = Va[t];
  __syncthreads();

  // Xw = X@W, Xu = X@U.  h = lane (fixed per thread) -> W/U column regs reused 8x.
  {
    const int h = t & 63, iw = t >> 6;
    float aw[8] = {0,0,0,0,0,0,0,0}, au[8] = {0,0,0,0,0,0,0,0};
    for (int f = 0; f < 64; ++f) {
      float wv_ = Wa[f * 64 + h], uv_ = Ua[f * 64 + h];
#pragma unroll
      for (int s = 0; s < 8; ++s) {
        float x = Xs[iw + 4 * s][f];
        aw[s] = fmaf(x, wv_, aw[s]);
        au[s] = fmaf(x, uv_, au[s]);
      }
    }
#pragma unroll
    for (int s = 0; s < 8; ++s) { Xw[iw + 4 * s][h] = aw[s]; Xu[iw + 4 * s][h] = au[s]; }
  }
  __syncthreads();

  // e[i][j] = sum_h tanh(Xw[i][h]+Xu[j][h]) * V[h]
  for (int p = t; p < 1024; p += 256) {
    int i = p >> 5, j = p & 31;
    float acc = 0.f;
    for (int h = 0; h < 64; ++h) {
      float s  = Xw[i][h] + Xu[j][h];
      float ex = __expf(2.f * s);
      float th = 1.f - 2.f * __builtin_amdgcn_rcpf(ex + 1.f);
      acc = fmaf(th, Vs[h], acc);
    }
    ev[i][j] = acc;
  }
  __syncthreads();

  // softmax over j: 32 rows x 8 threads
  {
    int i = t >> 3, g = t & 7;
    float e0 = ev[i][g], e1 = ev[i][g + 8], e2 = ev[i][g + 16], e3 = ev[i][g + 24];
    float m = fmaxf(fmaxf(e0, e1), fmaxf(e2, e3));
    m = fmaxf(m, __shfl_xor(m, 1));
    m = fmaxf(m, __shfl_xor(m, 2));
    m = fmaxf(m, __shfl_xor(m, 4));
    float p0 = __expf(e0 - m), p1 = __expf(e1 - m), p2 = __expf(e2 - m), p3 = __expf(e3 - m);
    float s = p0 + p1 + p2 + p3;
    s += __shfl_xor(s, 1); s += __shfl_xor(s, 2); s += __shfl_xor(s, 4);
    float inv = __builtin_amdgcn_rcpf(s);
    ev[i][g] = p0 * inv; ev[i][g + 8] = p1 * inv; ev[i][g + 16] = p2 * inv; ev[i][g + 24] = p3 * inv;
  }
  __syncthreads();

  // c = alpha@X - diag(alpha)*X ; ins = [X | c]
  for (int p = t; p < 2048; p += 256) {
    int i = p >> 6, f = p & 63;
    float acc = 0.f;
#pragma unroll 8
    for (int j = 0; j < 32; ++j) acc = fmaf(ev[i][j], Xs[j][f], acc);
    acc -= ev[i][i] * Xs[i][f];
    ins[i][f]      = Xs[i][f];
    ins[i][64 + f] = acc;
  }
  __syncthreads();

  // conv 2x2 VALID + relu -> flat bf16 (k = f*3937 + r*127 + c)
  // position outer, 8-filter tile inner: 4 LDS tap reads amortized over 8 filters
  const int lane = t & 63, wv = t >> 6;
  u16* fb = flat + (size_t)b * FLATD;
  for (int fblk = 0; fblk < 8; ++fblk) {
    float w00[8], w01[8], w10[8], w11[8], bb[8];
#pragma unroll
    for (int j = 0; j < 8; ++j) {
      int f = fblk * 8 + j;
      w00[j] = cw[f * 4 + 0]; w01[j] = cw[f * 4 + 1];
      w10[j] = cw[f * 4 + 2]; w11[j] = cw[f * 4 + 3];
      bb[j]  = cb[f];
    }
    for (int s = wv; s < 62; s += 4) {
      int r = s >> 1;
      int c = ((s & 1) << 6) + lane;
      if (c < 127) {
        float x0 = ins[r][c],     x1 = ins[r][c + 1];
        float y0 = ins[r + 1][c], y1 = ins[r + 1][c + 1];
        u16* po = fb + (size_t)(fblk * 8) * 3937 + r * 127 + c;
#pragma unroll
        for (int j = 0; j < 8; ++j) {
          float y = fmaf(x0, w00[j], fmaf(x1, w01[j],
                    fmaf(y0, w10[j], fmaf(y1, w11[j], bb[j]))));
          po[(size_t)j * 3937] = f2bf(fmaxf(y, 0.f));
        }
      }
    }
  }
}

// ---------------------------------------------------------------------------
// K2: w1 (f32, rows of LIN1) -> w1b (bf16, rows of K_, cate tail dropped)
// ---------------------------------------------------------------------------
__global__ __launch_bounds__(256) void k_cast_w1(const float* __restrict__ w1,
                                                 u16* __restrict__ w1b)
{
  const int o = blockIdx.x;     // 256 rows
  const int part = blockIdx.y;  // 8 parts of 7874 float4s
  const int t = threadIdx.x;
  const float4* src = (const float4*)(w1 + (size_t)o * LIN1) + part * 7874;
  u16x4* dst = (u16x4*)(w1b + (size_t)o * K_) + part * 7874;
  for (int i = t; i < 7874; i += 256) {
    float4 v = src[i];
    u16x4 o4;
    o4.x = f2bf(v.x); o4.y = f2bf(v.y); o4.z = f2bf(v.z); o4.w = f2bf(v.w);
    dst[i] = o4;
  }
}

// ---------------------------------------------------------------------------
// K3: x1 = b1 + cate_embedding . w1[:, FLATD:]  (f32, exact)
// ---------------------------------------------------------------------------
__global__ __launch_bounds__(256) void k_cate(
    const int* __restrict__ Xc, const float* __restrict__ e0,
    const float* __restrict__ e1, const float* __restrict__ e2,
    const float* __restrict__ w1, const float* __restrict__ b1,
    float* __restrict__ x1)
{
  __shared__ float es[24];
  const int b = blockIdx.x, t = threadIdx.x;
  if (t < 24) {
    int g = t >> 3, d = t & 7;
    int idx = Xc[b * 3 + g];
    const float* tab = (g == 0) ? e0 : (g == 1) ? e1 : e2;
    es[t] = tab[idx * 8 + d];
  }
  __syncthreads();
  float acc = b1[t];
  const float* wt = w1 + (size_t)t * LIN1 + FLATD;
#pragma unroll
  for (int j = 0; j < 24; ++j) acc = fmaf(es[j], wt[j], acc);
  x1[b * 256 + t] = acc;
}

// ---------------------------------------------------------------------------
// K4: bf16 MFMA GEMM  x1[1024,256] += flat[1024,K] . w1b[256,K]^T
// BM=128, BN=256 (full N -> A fetched ONCE), BK=32, 8 waves (2x4, 64x64 each).
// Double-buffered LDS + counted vmcnt pipeline (T3-minimal + T4):
// prefetch K-step t+1 while computing t; vmcnt(3) never drains to 0 in loop.
// kc=127 chunks x 62 steps (127*62*32 = 251968 exact). grid 8x127 = 1016.
// ---------------------------------------------------------------------------
#define AS1 __attribute__((address_space(1)))
#define AS3 __attribute__((address_space(3)))
__device__ __forceinline__ void g2l16(const void* g, void* l) {
  __builtin_amdgcn_global_load_lds((const AS1 u32*)g, (AS3 u32*)l, 16, 0, 0);
}

__global__ __launch_bounds__(512, 4) void k_gemm(
    const u16* __restrict__ A, const u16* __restrict__ Bw, float* __restrict__ C)
{
  // per buffer: A region [0, 8KB) = 128 rows x 64B; B region [8KB, 24KB) = 256 rows x 64B
  __shared__ u16 lds[2][12288];  // 2 x 24 KB
  const int mt = blockIdx.x;    // 8
  const int kc = blockIdx.y;    // 127
  const int tid = threadIdx.x;
  const int lane = tid & 63, w = tid >> 6;   // 8 waves
  const int wm = w >> 2, wn = w & 3;         // 2x4 wave grid, wave tile 64x64

  const size_t kbase = (size_t)kc * 1984;    // 62*32
  // staging: each wave loads A rows [w*16, w*16+16) and B rows [w*32, w*32+32)
  const u16* gA  = A  + ((size_t)(mt * 128 + w * 16 + (lane >> 2))) * K_ + kbase + (size_t)(lane & 3) * 8;
  const u16* gB0 = Bw + ((size_t)(w * 32      + (lane >> 2))) * K_ + kbase + (size_t)(lane & 3) * 8;
  const u16* gB1 = Bw + ((size_t)(w * 32 + 16 + (lane >> 2))) * K_ + kbase + (size_t)(lane & 3) * 8;

  f32x4 acc[4][4] = {};

  const int aoff = (wm * 64 + (lane & 15)) * 64 + (lane >> 4) * 16;
  const int boff = 8192 + (wn * 64 + (lane & 15)) * 64 + (lane >> 4) * 16;

#define STAGE(T, R)                                                         \
  {                                                                         \
    const size_t ko = (size_t)(T) * 32;                                     \
    char* base = (char*)&lds[R][0];                                         \
    g2l16(gA  + ko, base + w * 1024);                                       \
    g2l16(gB0 + ko, base + 8192 + (2 * w) * 1024);                          \
    g2l16(gB1 + ko, base + 8192 + (2 * w + 1) * 1024);                      \
  }

#define COMPUTE(R)                                                          \
  {                                                                         \
    const char* base = (const char*)&lds[R][0];                             \
    s16x8 af[4], bf[4];                                                     \
    _Pragma("unroll")                                                       \
    for (int mi = 0; mi < 4; ++mi) af[mi] = *(const s16x8*)(base + aoff + mi * 1024); \
    _Pragma("unroll")                                                       \
    for (int ni = 0; ni < 4; ++ni) bf[ni] = *(const s16x8*)(base + boff + ni * 1024); \
    _Pragma("unroll")                                                       \
    for (int mi = 0; mi < 4; ++mi)                                          \
      _Pragma("unroll")                                                     \
      for (int ni = 0; ni < 4; ++ni)                                        \
        acc[mi][ni] = __builtin_amdgcn_mfma_f32_16x16x32_bf16(af[mi], bf[ni], acc[mi][ni], 0, 0, 0); \
  }

  STAGE(0, 0);
  for (int t = 0; t < 61; ++t) {
    STAGE(t + 1, (t + 1) & 1);
    asm volatile("s_waitcnt vmcnt(3)" ::: "memory");  // step t's 3 loads done; t+1's stay in flight
    __builtin_amdgcn_sched_barrier(0);
    __builtin_amdgcn_s_barrier();
    asm volatile("" ::: "memory");
    COMPUTE(t & 1);
    asm volatile("" ::: "memory");
    __builtin_amdgcn_s_barrier();   // all waves done reading buf[t&1] before it's restaged
    asm volatile("" ::: "memory");
  }
  asm volatile("s_waitcnt vmcnt(0)" ::: "memory");
  __builtin_amdgcn_sched_barrier(0);
  __builtin_amdgcn_s_barrier();
  asm volatile("" ::: "memory");
  COMPUTE(1);

#undef STAGE
#undef COMPUTE

  // D layout (m89-verified): n = lane&15, m = (lane>>4)*4 + reg
  const int m0 = mt * 128 + wm * 64 + ((lane >> 4) << 2);
  const int n0 = wn * 64 + (lane & 15);
#pragma unroll
  for (int mi = 0; mi < 4; ++mi)
#pragma unroll
    for (int ni = 0; ni < 4; ++ni)
#pragma unroll
      for (int r = 0; r < 4; ++r)
        atomicAdd(C + (size_t)(m0 + mi * 16 + r) * 256 + (n0 + ni * 16), acc[mi][ni][r]);
}

// ---------------------------------------------------------------------------
// K5: out = relu(relu(x1) @ w2^T + b2) @ w3^T + b3
// ---------------------------------------------------------------------------
__global__ __launch_bounds__(64) void k_tail(
    const float* __restrict__ x1, const float* __restrict__ w2, const float* __restrict__ b2,
    const float* __restrict__ w3, const float* __restrict__ b3, float* __restrict__ out)
{
  __shared__ float x2s[32];
  const int b = blockIdx.x, l = threadIdx.x;
  const int j = l & 31, og = l >> 5;
  const float* xb = x1 + b * 256 + og * 128;
  const float* wr = w2 + j * 256 + og * 128;
  float acc = 0.f;
#pragma unroll 4
  for (int i = 0; i < 128; ++i)
    acc = fmaf(fmaxf(xb[i], 0.f), wr[i], acc);
  acc += __shfl_xor(acc, 32);
  if (og == 0) x2s[j] = fmaxf(acc + b2[j], 0.f);
  __syncthreads();
  if (l < 2) {
    float r = b3[l];
#pragma unroll
    for (int q = 0; q < 32; ++q) r = fmaf(x2s[q], w3[l * 32 + q], r);
    out[(size_t)b * 2 + l] = r;
  }
}

// ---------------------------------------------------------------------------
extern "C" void kernel_launch(void* const* d_in, const int* in_sizes, int n_in,
                              void* d_out, int out_size, void* d_ws, size_t ws_size,
                              hipStream_t stream)
{
  const float* Xn = (const float*)d_in[0];
  const int*   Xc = (const int*)d_in[1];
  const float* Wa = (const float*)d_in[2];
  const float* Ua = (const float*)d_in[3];
  const float* Va = (const float*)d_in[4];
  const float* cw = (const float*)d_in[5];
  const float* cb = (const float*)d_in[6];
  const float* e0 = (const float*)d_in[7];
  const float* e1 = (const float*)d_in[8];
  const float* e2 = (const float*)d_in[9];
  const float* w1 = (const float*)d_in[10];
  const float* b1 = (const float*)d_in[11];
  const float* w2 = (const float*)d_in[12];
  const float* b2 = (const float*)d_in[13];
  const float* w3 = (const float*)d_in[14];
  const float* b3 = (const float*)d_in[15];
  float* out = (float*)d_out;

  char* ws = (char*)d_ws;
  u16*   flat = (u16*)ws;                      // 1024*251968*2 = 516,030,464 B
  u16*   w1b  = (u16*)(ws + 516030464ull);     // 256*251968*2  = 129,007,616 B
  float* x1   = (float*)(ws + 645038080ull);   // 1024*256*4    =   1,048,576 B
  if (ws_size < 646086656ull) return;          // insufficient scratch: bail visibly

  k_attn_conv<<<dim3(1024), dim3(256), 0, stream>>>(Xn, Wa, Ua, Va, cw, cb, flat);
  k_cast_w1 <<<dim3(256, 8), dim3(256), 0, stream>>>(w1, w1b);
  k_cate    <<<dim3(1024), dim3(256), 0, stream>>>(Xc, e0, e1, e2, w1, b1, x1);
  k_gemm    <<<dim3(8, 127), dim3(512), 0, stream>>>(flat, w1b, x1);
  k_tail    <<<dim3(1024), dim3(64), 0, stream>>>(x1, w2, b2, w3, b3, out);
}